// Round 1
// baseline (4209.569 us; speedup 1.0000x reference)
//
#include <hip/hip_runtime.h>

#define NTOK   32768
#define DDIM   512
#define KCODES 8192
#define DK     (DDIM * KCODES)      // 4194304
#define DECAYF 0.8f
#define EPSF   1e-5f
#define FLTMAX 3.402823466e38f

// ---------------- ws layout (float offsets) ----------------
#define WS_ESUMT   0                        // [K][D] segment-sum accumulator (zeroed)
#define WS_ONEHOT  DK                       // [K] (zeroed)
#define WS_ENORM   (DK + KCODES)            // [K] (zeroed, atomic accum)
#define WS_SCAL    (DK + 2 * KCODES)        // [16]: 0=loss accum, 1=nsum (zeroed)
#define WS_PART    (DK + 2 * KCODES + 16)   // 4 slices * NTOK u64 candidates
#define WS_EMBEDT  (WS_PART + 8 * NTOK)     // [K][D] transposed codebook
#define WS_ZERO_BYTES ((size_t)(DK + 2 * KCODES + 16) * 4)

// ============ K2: tiled transpose embed[D][K] -> embedT[K][D], fused e_norm ============
__global__ __launch_bounds__(256) void transpose_enorm_kernel(
    const float* __restrict__ embed, float* __restrict__ embedT,
    float* __restrict__ e_norm) {
  __shared__ float tile[32][33];
  __shared__ float part[8][32];
  const int k0 = blockIdx.x * 32;
  const int d0 = blockIdx.y * 32;
  const int tx = threadIdx.x;   // 0..31
  const int ty = threadIdx.y;   // 0..7
  float sq = 0.f;
#pragma unroll
  for (int j = 0; j < 4; ++j) {
    const int dl = ty + j * 8;
    const float v = embed[(size_t)(d0 + dl) * KCODES + k0 + tx];
    tile[dl][tx] = v;
    sq += v * v;
  }
  part[ty][tx] = sq;
  __syncthreads();
  if (ty == 0) {
    float s = 0.f;
#pragma unroll
    for (int j = 0; j < 8; ++j) s += part[j][tx];
    atomicAdd(&e_norm[k0 + tx], s);
  }
#pragma unroll
  for (int j = 0; j < 4; ++j) {
    const int kl = ty + j * 8;
    embedT[(size_t)(k0 + kl) * DDIM + d0 + tx] = tile[tx][kl];
  }
}

// ============ K3: fused dist-GEMM + running argmin (fp32 VALU) ============
// Tile: 128 tokens x 128 codes, D-chunk 32, 256 threads, 8x8 micro-tile.
// Grid: (NTOK/128, 4 K-slices). Each block scans K/4=2048 codes.
#define TM 128
#define TN 128
#define DB 32
#define PA 132   // padded LDS stride for A (bank-conflict mitigation + 16B align)

__global__ __launch_bounds__(256, 2) void argmin_gemm_kernel(
    const float* __restrict__ x, const float* __restrict__ embed,
    const float* __restrict__ e_norm, unsigned long long* __restrict__ partials) {
  __shared__ float As[DB * PA];   // As[dd*PA + i]  (A transposed: d-major)
  __shared__ float Bs[DB * TN];   // Bs[dd*TN + kk]

  const int t  = threadIdx.x;
  const int tx = t & 15;   // code micro-col group
  const int ty = t >> 4;   // token micro-row group
  const int n0 = blockIdx.x * TM;
  const int kslice = blockIdx.y;             // 0..3
  const int kbase  = kslice * (KCODES / 4);  // 2048-code slice

  const int la_f4  = t & 7;    // which float4 within a 32-float d-chunk row
  const int la_row = t >> 3;   // 0..31
  const int lb_k4  = (t & 31) * 4;
  const int lb_row = t >> 5;   // 0..7

  float bestD[8];
  int   bestI[8];
#pragma unroll
  for (int i = 0; i < 8; ++i) { bestD[i] = FLTMAX; bestI[i] = 0; }

  for (int kt = 0; kt < KCODES / 4; kt += TN) {   // 16 code-tiles
    float acc[8][8];
#pragma unroll
    for (int i = 0; i < 8; ++i)
#pragma unroll
      for (int j = 0; j < 8; ++j) acc[i][j] = 0.f;

    for (int d0 = 0; d0 < DDIM; d0 += DB) {   // 16 D-chunks
      __syncthreads();
      // stage A (x tile), transposed into LDS
#pragma unroll
      for (int p = 0; p < 4; ++p) {
        const int i = la_row + p * 32;
        const float4 v = *(const float4*)&x[(size_t)(n0 + i) * DDIM + d0 + la_f4 * 4];
        const int dd = la_f4 * 4;
        As[(dd + 0) * PA + i] = v.x;
        As[(dd + 1) * PA + i] = v.y;
        As[(dd + 2) * PA + i] = v.z;
        As[(dd + 3) * PA + i] = v.w;
      }
      // stage B (embed tile), already d-major
#pragma unroll
      for (int p = 0; p < 4; ++p) {
        const int dd = lb_row + p * 8;
        const float4 v = *(const float4*)&embed[(size_t)(d0 + dd) * KCODES + kbase + kt + lb_k4];
        *(float4*)&Bs[dd * TN + lb_k4] = v;
      }
      __syncthreads();
#pragma unroll 8
      for (int d = 0; d < DB; ++d) {
        const float4 a0 = *(const float4*)&As[d * PA + ty * 8];
        const float4 a1 = *(const float4*)&As[d * PA + ty * 8 + 4];
        const float4 b0 = *(const float4*)&Bs[d * TN + tx * 8];
        const float4 b1 = *(const float4*)&Bs[d * TN + tx * 8 + 4];
        const float a[8] = {a0.x, a0.y, a0.z, a0.w, a1.x, a1.y, a1.z, a1.w};
        const float b[8] = {b0.x, b0.y, b0.z, b0.w, b1.x, b1.y, b1.z, b1.w};
#pragma unroll
        for (int i = 0; i < 8; ++i)
#pragma unroll
          for (int j = 0; j < 8; ++j)
            acc[i][j] = fmaf(a[i], b[j], acc[i][j]);
      }
    }
    // scores for this code-tile; update running min (k ascending => strict < keeps first)
#pragma unroll
    for (int j = 0; j < 8; ++j) {
      const int k = kbase + kt + tx * 8 + j;
      const float en = e_norm[k];
#pragma unroll
      for (int i = 0; i < 8; ++i) {
        const float s = en - 2.0f * acc[i][j];
        if (s < bestD[i]) { bestD[i] = s; bestI[i] = k; }
      }
    }
  }

  __syncthreads();
  // cross-thread (tx) reduction via packed u64 keys; reuse As as scratch (16KB <= 16.9KB)
  unsigned long long* red = (unsigned long long*)As;
#pragma unroll
  for (int i = 0; i < 8; ++i) {
    unsigned u = __float_as_uint(bestD[i]);
    u = (u & 0x80000000u) ? ~u : (u | 0x80000000u);   // orderable float bits
    red[(ty * 8 + i) * 16 + tx] =
        ((unsigned long long)u << 32) | (unsigned)bestI[i];
  }
  __syncthreads();
  if (t < TM) {
    unsigned long long m = red[t * 16];
#pragma unroll
    for (int j = 1; j < 16; ++j) {
      const unsigned long long c = red[t * 16 + j];
      m = (c < m) ? c : m;
    }
    partials[(size_t)kslice * NTOK + n0 + t] = m;
  }
}

// ============ K4: final argmin merge + gather quantize + EMA scatter stats ============
__global__ __launch_bounds__(128) void gather_stats_kernel(
    const float* __restrict__ x, const float* __restrict__ embedT,
    const unsigned long long* __restrict__ partials,
    float* __restrict__ quant_out, float* __restrict__ indf_out,
    float* __restrict__ embed_sumT, float* __restrict__ onehot,
    float* __restrict__ scal) {
  const int n = blockIdx.x;
  __shared__ int s_ind;
  __shared__ float wsum[2];
  if (threadIdx.x == 0) {
    unsigned long long m = partials[n];
#pragma unroll
    for (int s = 1; s < 4; ++s) {
      const unsigned long long c = partials[(size_t)s * NTOK + n];
      m = (c < m) ? c : m;
    }
    const int k = (int)(m & 0xFFFFFFFFull);
    s_ind = k;
    indf_out[n] = (float)k;
    atomicAdd(&onehot[k], 1.0f);
  }
  __syncthreads();
  const int k = s_ind;
  const int d4 = threadIdx.x * 4;    // 128 threads * 4 = 512 = DDIM exactly
  const float4 e  = *(const float4*)&embedT[(size_t)k * DDIM + d4];
  const float4 xv = *(const float4*)&x[(size_t)n * DDIM + d4];
  *(float4*)&quant_out[(size_t)n * DDIM + d4] = e;
  atomicAdd(&embed_sumT[(size_t)k * DDIM + d4 + 0], xv.x);
  atomicAdd(&embed_sumT[(size_t)k * DDIM + d4 + 1], xv.y);
  atomicAdd(&embed_sumT[(size_t)k * DDIM + d4 + 2], xv.z);
  atomicAdd(&embed_sumT[(size_t)k * DDIM + d4 + 3], xv.w);
  const float dx0 = e.x - xv.x, dx1 = e.y - xv.y, dx2 = e.z - xv.z, dx3 = e.w - xv.w;
  float ls = dx0 * dx0 + dx1 * dx1 + dx2 * dx2 + dx3 * dx3;
#pragma unroll
  for (int off = 32; off > 0; off >>= 1) ls += __shfl_down(ls, off);
  if ((threadIdx.x & 63) == 0) wsum[threadIdx.x >> 6] = ls;
  __syncthreads();
  if (threadIdx.x == 0) atomicAdd(&scal[0], wsum[0] + wsum[1]);
}

// ============ K5: cluster-size EMA + total-count reduction ============
__global__ __launch_bounds__(256) void cluster_kernel(
    const float* __restrict__ cluster_size, const float* __restrict__ onehot,
    float* __restrict__ ncs_out, float* __restrict__ scal) {
  const int k = blockIdx.x * 256 + threadIdx.x;
  const float v = cluster_size[k] * DECAYF + (1.0f - DECAYF) * onehot[k];
  ncs_out[k] = v;
  float s = v;
#pragma unroll
  for (int off = 32; off > 0; off >>= 1) s += __shfl_down(s, off);
  __shared__ float w[4];
  if ((threadIdx.x & 63) == 0) w[threadIdx.x >> 6] = s;
  __syncthreads();
  if (threadIdx.x == 0) atomicAdd(&scal[1], w[0] + w[1] + w[2] + w[3]);
}

// ============ K6: new_embed_avg + new_embed + loss write ============
// NOTE: out3/out5 start at an ODD float offset -> scalar accesses only.
__global__ __launch_bounds__(256) void finalize_kernel(
    const float* __restrict__ embed_avg, const float* __restrict__ embed_sumT,
    const float* __restrict__ ncs, const float* __restrict__ scal,
    float* __restrict__ out_embed, float* __restrict__ out_avg,
    float* __restrict__ out_loss) {
  const int idx = blockIdx.x * 256 + threadIdx.x;   // 0..DK-1, [D][K] layout
  const int d = idx >> 13;
  const int k = idx & (KCODES - 1);
  const float ea = embed_avg[idx];
  const float es = embed_sumT[(size_t)k * DDIM + d];
  const float nea = DECAYF * ea + (1.0f - DECAYF) * es;
  out_avg[idx] = nea;
  const float nsum = scal[1];
  const float cs = (ncs[k] + EPSF) / (nsum + (float)KCODES * EPSF) * nsum;
  out_embed[idx] = nea / cs;
  if (idx == 0) out_loss[0] = scal[0] * (1.0f / ((float)NTOK * (float)DDIM));
}

extern "C" void kernel_launch(void* const* d_in, const int* in_sizes, int n_in,
                              void* d_out, int out_size, void* d_ws, size_t ws_size,
                              hipStream_t stream) {
  (void)in_sizes; (void)n_in; (void)out_size; (void)ws_size;
  const float* x            = (const float*)d_in[0];   // [B,T,D] = [NTOK, 512]
  const float* embed        = (const float*)d_in[1];   // [D, K]
  const float* cluster_size = (const float*)d_in[2];   // [K]
  const float* embed_avg    = (const float*)d_in[3];   // [D, K]

  float* out = (float*)d_out;
  float* out_quant = out;                               // 16777216
  float* out_indf  = out + 16777216;                    // 32768
  float* out_loss  = out + 16777216 + 32768;            // 1
  float* out_embed = out + 16777216 + 32768 + 1;        // 4194304 (odd offset!)
  float* out_ncs   = out_embed + DK;                    // 8192
  float* out_avg   = out_ncs + KCODES;                  // 4194304

  float* ws = (float*)d_ws;
  float* esumT   = ws + WS_ESUMT;
  float* onehot  = ws + WS_ONEHOT;
  float* e_norm  = ws + WS_ENORM;
  float* scal    = ws + WS_SCAL;
  unsigned long long* partials = (unsigned long long*)(ws + WS_PART);
  float* embedT  = ws + WS_EMBEDT;

  // K1: zero the atomic-accumulator regions (ws is poisoned 0xAA every call)
  hipMemsetAsync(d_ws, 0, WS_ZERO_BYTES, stream);

  // K2: transpose codebook + code norms
  transpose_enorm_kernel<<<dim3(KCODES / 32, DDIM / 32), dim3(32, 8), 0, stream>>>(
      embed, embedT, e_norm);

  // K3: distance GEMM + per-slice argmin
  argmin_gemm_kernel<<<dim3(NTOK / TM, 4), 256, 0, stream>>>(
      x, embed, e_norm, partials);

  // K4: merge slices, gather quantize, scatter EMA stats, loss partials
  gather_stats_kernel<<<NTOK, 128, 0, stream>>>(
      x, embedT, partials, out_quant, out_indf, esumT, onehot, scal);

  // K5: cluster-size EMA + nsum
  cluster_kernel<<<KCODES / 256, 256, 0, stream>>>(cluster_size, onehot, out_ncs, scal);

  // K6: finalize new_embed_avg / new_embed / loss
  finalize_kernel<<<DK / 256, 256, 0, stream>>>(
      embed_avg, esumT, out_ncs, scal, out_embed, out_avg, out_loss);
}

// Round 2
// 1996.591 us; speedup vs baseline: 2.1084x; 2.1084x over previous
//
#include <hip/hip_runtime.h>

#define NTOK   32768
#define DDIM   512
#define KCODES 8192
#define DK     (DDIM * KCODES)      // 4194304
#define DECAYF 0.8f
#define EPSF   1e-5f

using short8 = __attribute__((ext_vector_type(8))) short;
using f32x4  = __attribute__((ext_vector_type(4))) float;

// ---------------- ws layout (float offsets) ----------------
#define WS_ESUMT   0                          // [K][D] fp32 accum (zeroed)
#define WS_ONEHOT  DK                         // [K] (zeroed)
#define WS_ENORM   (DK + 8192)                // [K] (zeroed, atomic accum)
#define WS_SCAL    (DK + 16384)               // [16]: 0=loss, 1=nsum (zeroed)
#define WS_PART    (DK + 16400)               // 64 slices * NTOK u64
#define WS_EMBEDT  (WS_PART + 2 * 64 * NTOK)  // [K][D] fp32 transposed codebook
#define WS_EHI     (WS_EMBEDT + DK)           // [K][D] bf16 hi (DK ushorts)
#define WS_ELO     (WS_EHI + DK / 2)          // [K][D] bf16 lo
#define WS_ZERO_BYTES ((size_t)(DK + 16400) * 4)

__device__ __forceinline__ unsigned short bf16rne(float f) {
  unsigned u = __float_as_uint(f);
  unsigned r = u + 0x7FFFu + ((u >> 16) & 1u);
  return (unsigned short)(r >> 16);
}

__device__ __forceinline__ void gload_lds16(const unsigned short* g, unsigned short* l) {
  __builtin_amdgcn_global_load_lds(
      (const __attribute__((address_space(1))) unsigned int*)g,
      (__attribute__((address_space(3))) unsigned int*)l, 16, 0, 0);
}

// ============ K1: split x into bf16 hi/lo (exact: hi+lo+tiny residual) ============
__global__ __launch_bounds__(256) void split_x_kernel(
    const float* __restrict__ x, unsigned short* __restrict__ hi,
    unsigned short* __restrict__ lo) {
  const size_t i = ((size_t)blockIdx.x * 256 + threadIdx.x) * 8;
  const float4 v0 = *(const float4*)&x[i];
  const float4 v1 = *(const float4*)&x[i + 4];
  const float v[8] = {v0.x, v0.y, v0.z, v0.w, v1.x, v1.y, v1.z, v1.w};
  unsigned short h[8], l[8];
#pragma unroll
  for (int j = 0; j < 8; ++j) {
    h[j] = bf16rne(v[j]);
    l[j] = bf16rne(v[j] - __uint_as_float((unsigned)h[j] << 16));
  }
  uint4 H, L;
  H.x = h[0] | ((unsigned)h[1] << 16); H.y = h[2] | ((unsigned)h[3] << 16);
  H.z = h[4] | ((unsigned)h[5] << 16); H.w = h[6] | ((unsigned)h[7] << 16);
  L.x = l[0] | ((unsigned)l[1] << 16); L.y = l[2] | ((unsigned)l[3] << 16);
  L.z = l[4] | ((unsigned)l[5] << 16); L.w = l[6] | ((unsigned)l[7] << 16);
  *(uint4*)&hi[i] = H;
  *(uint4*)&lo[i] = L;
}

// ============ K2: transpose embed [D][K]->[K][D] fp32 + bf16 hi/lo + e_norm ============
__global__ __launch_bounds__(256) void transpose_split_kernel(
    const float* __restrict__ embed, float* __restrict__ embedT,
    unsigned short* __restrict__ ehi, unsigned short* __restrict__ elo,
    float* __restrict__ e_norm) {
  __shared__ float tile[32][33];
  __shared__ float part[8][32];
  const int k0 = blockIdx.x * 32;
  const int d0 = blockIdx.y * 32;
  const int tx = threadIdx.x;   // 0..31
  const int ty = threadIdx.y;   // 0..7
  float sq = 0.f;
#pragma unroll
  for (int j = 0; j < 4; ++j) {
    const int dl = ty + j * 8;
    const float v = embed[(size_t)(d0 + dl) * KCODES + k0 + tx];
    tile[dl][tx] = v;
    sq += v * v;
  }
  part[ty][tx] = sq;
  __syncthreads();
  if (ty == 0) {
    float s = 0.f;
#pragma unroll
    for (int j = 0; j < 8; ++j) s += part[j][tx];
    atomicAdd(&e_norm[k0 + tx], s);
  }
#pragma unroll
  for (int j = 0; j < 4; ++j) {
    const int kl = ty + j * 8;
    const size_t idx = (size_t)(k0 + kl) * DDIM + d0 + tx;
    const float v = tile[tx][kl];
    embedT[idx] = v;
    const unsigned short h = bf16rne(v);
    ehi[idx] = h;
    elo[idx] = bf16rne(v - __uint_as_float((unsigned)h << 16));
  }
}

// ============ K3: bf16-split MFMA dist GEMM + fused argmin ============
// C-tile 128 tokens x 128 codes, BK=32, 4 passes (hi*hi, hi*lo, lo*hi, lo*lo).
// Grid: (64 k-slices, 256 token-tiles) -- k fastest for x-tile L2 reuse.
__global__ __launch_bounds__(256, 2) void argmin_mfma_kernel(
    const unsigned short* __restrict__ xhi, const unsigned short* __restrict__ xlo,
    const unsigned short* __restrict__ ehi, const unsigned short* __restrict__ elo,
    const float* __restrict__ e_norm, unsigned long long* __restrict__ partials) {
  __shared__ unsigned short As[128 * 32];   // [token][k] bf16, 8 KB
  __shared__ unsigned short Bs[128 * 32];   // [code][k]  bf16, 8 KB

  const int t    = threadIdx.x;
  const int wid  = t >> 6;
  const int lid  = t & 63;
  const int kblk = blockIdx.x;              // 0..63
  const int tokbase = blockIdx.y * 128;
  const int kbase   = kblk * 128;

  const int wrow = wid >> 1, wcol = wid & 1;    // 2x2 wave grid, 64x64 each
  const int m16  = lid & 15, kq = lid >> 4;

  const int srow = lid >> 2;          // staging row-within-chunk
  const int scol = (lid & 3) * 8;     // staging col (ushorts)

  f32x4 acc[4][4];
#pragma unroll
  for (int i = 0; i < 4; ++i)
#pragma unroll
    for (int j = 0; j < 4; ++j) acc[i][j] = (f32x4)0.f;

  const unsigned short* APASS[4] = {xhi, xhi, xlo, xlo};
  const unsigned short* BPASS[4] = {ehi, elo, ehi, elo};

#pragma unroll 1
  for (int pass = 0; pass < 4; ++pass) {
    const unsigned short* Ag = APASS[pass] + (size_t)tokbase * DDIM;
    const unsigned short* Bg = BPASS[pass] + (size_t)kbase * DDIM;
#pragma unroll 1
    for (int d0 = 0; d0 < DDIM; d0 += 32) {
      __syncthreads();
#pragma unroll
      for (int p = 0; p < 2; ++p) {
        const int chunk = wid + p * 4;                       // wave-uniform
        const int go = (chunk * 16 + srow) * DDIM + d0 + scol;
        gload_lds16(Ag + go, &As[chunk * 512]);
        gload_lds16(Bg + go, &Bs[chunk * 512]);
      }
      __syncthreads();
      short8 a[4], b[4];
#pragma unroll
      for (int i = 0; i < 4; ++i)
        a[i] = *(const short8*)&As[(wrow * 64 + i * 16 + m16) * 32 + kq * 8];
#pragma unroll
      for (int j = 0; j < 4; ++j)
        b[j] = *(const short8*)&Bs[(wcol * 64 + j * 16 + m16) * 32 + kq * 8];
#pragma unroll
      for (int i = 0; i < 4; ++i)
#pragma unroll
        for (int j = 0; j < 4; ++j)
          acc[i][j] = __builtin_amdgcn_mfma_f32_16x16x32_bf16(a[i], b[j], acc[i][j], 0, 0, 0);
    }
  }

  // ---- fused argmin epilogue: score = e_norm[k] - 2*dot ----
  float en[4];
#pragma unroll
  for (int j = 0; j < 4; ++j)
    en[j] = e_norm[kbase + wcol * 64 + j * 16 + m16];

  __syncthreads();
  unsigned long long* red = (unsigned long long*)As;   // [128][2], 2 KB
#pragma unroll
  for (int i = 0; i < 4; ++i) {
#pragma unroll
    for (int r = 0; r < 4; ++r) {
      unsigned long long best = 0xFFFFFFFFFFFFFFFFull;
#pragma unroll
      for (int j = 0; j < 4; ++j) {
        const float s = en[j] - 2.0f * acc[i][j][r];
        unsigned u = __float_as_uint(s);
        u = (u & 0x80000000u) ? ~u : (u | 0x80000000u);  // orderable bits
        const unsigned k = (unsigned)(kbase + wcol * 64 + j * 16 + m16);
        const unsigned long long c = ((unsigned long long)u << 32) | k;
        best = (c < best) ? c : best;
      }
      // min across the 16 lanes sharing this C-row (they hold the 16 cols)
#pragma unroll
      for (int s = 1; s < 16; s <<= 1) {
        const unsigned long long c = __shfl_xor(best, s);
        best = (c < best) ? c : best;
      }
      if (m16 == 0)
        red[(wrow * 64 + i * 16 + kq * 4 + r) * 2 + wcol] = best;
    }
  }
  __syncthreads();
  if (t < 128) {
    const unsigned long long a0 = red[t * 2], a1 = red[t * 2 + 1];
    partials[(size_t)kblk * NTOK + tokbase + t] = (a0 < a1) ? a0 : a1;
  }
}

// ============ K4: merge 64 slices + gather quantize + EMA scatter stats ============
__global__ __launch_bounds__(128) void gather_stats_kernel(
    const float* __restrict__ x, const float* __restrict__ embedT,
    const unsigned long long* __restrict__ partials,
    float* __restrict__ quant_out, float* __restrict__ indf_out,
    float* __restrict__ embed_sumT, float* __restrict__ onehot,
    float* __restrict__ scal) {
  const int n = blockIdx.x;
  __shared__ int s_ind;
  __shared__ float wsum[2];
  if (threadIdx.x < 64) {
    unsigned long long m = partials[(size_t)threadIdx.x * NTOK + n];
#pragma unroll
    for (int s = 32; s > 0; s >>= 1) {
      const unsigned long long c = __shfl_xor(m, s);
      m = (c < m) ? c : m;
    }
    if (threadIdx.x == 0) {
      const int k = (int)(m & 0xFFFFFFFFull);
      s_ind = k;
      indf_out[n] = (float)k;
      atomicAdd(&onehot[k], 1.0f);
    }
  }
  __syncthreads();
  const int k = s_ind;
  const int d4 = threadIdx.x * 4;    // 128 threads * 4 = 512 = DDIM
  const float4 e  = *(const float4*)&embedT[(size_t)k * DDIM + d4];
  const float4 xv = *(const float4*)&x[(size_t)n * DDIM + d4];
  *(float4*)&quant_out[(size_t)n * DDIM + d4] = e;
  atomicAdd(&embed_sumT[(size_t)k * DDIM + d4 + 0], xv.x);
  atomicAdd(&embed_sumT[(size_t)k * DDIM + d4 + 1], xv.y);
  atomicAdd(&embed_sumT[(size_t)k * DDIM + d4 + 2], xv.z);
  atomicAdd(&embed_sumT[(size_t)k * DDIM + d4 + 3], xv.w);
  const float dx0 = e.x - xv.x, dx1 = e.y - xv.y, dx2 = e.z - xv.z, dx3 = e.w - xv.w;
  float ls = dx0 * dx0 + dx1 * dx1 + dx2 * dx2 + dx3 * dx3;
#pragma unroll
  for (int off = 32; off > 0; off >>= 1) ls += __shfl_down(ls, off);
  if ((threadIdx.x & 63) == 0) wsum[threadIdx.x >> 6] = ls;
  __syncthreads();
  if (threadIdx.x == 0) atomicAdd(&scal[0], wsum[0] + wsum[1]);
}

// ============ K5: cluster-size EMA + total-count reduction ============
__global__ __launch_bounds__(256) void cluster_kernel(
    const float* __restrict__ cluster_size, const float* __restrict__ onehot,
    float* __restrict__ ncs_out, float* __restrict__ scal) {
  const int k = blockIdx.x * 256 + threadIdx.x;
  const float v = cluster_size[k] * DECAYF + (1.0f - DECAYF) * onehot[k];
  ncs_out[k] = v;
  float s = v;
#pragma unroll
  for (int off = 32; off > 0; off >>= 1) s += __shfl_down(s, off);
  __shared__ float w[4];
  if ((threadIdx.x & 63) == 0) w[threadIdx.x >> 6] = s;
  __syncthreads();
  if (threadIdx.x == 0) atomicAdd(&scal[1], w[0] + w[1] + w[2] + w[3]);
}

// ============ K6: new_embed_avg + new_embed + loss (odd offset -> scalar) ============
__global__ __launch_bounds__(256) void finalize_kernel(
    const float* __restrict__ embed_avg, const float* __restrict__ embed_sumT,
    const float* __restrict__ ncs, const float* __restrict__ scal,
    float* __restrict__ out_embed, float* __restrict__ out_avg,
    float* __restrict__ out_loss) {
  const int idx = blockIdx.x * 256 + threadIdx.x;   // [D][K] layout
  const int d = idx >> 13;
  const int k = idx & (KCODES - 1);
  const float ea = embed_avg[idx];
  const float es = embed_sumT[(size_t)k * DDIM + d];
  const float nea = DECAYF * ea + (1.0f - DECAYF) * es;
  out_avg[idx] = nea;
  const float nsum = scal[1];
  const float cs = (ncs[k] + EPSF) / (nsum + (float)KCODES * EPSF) * nsum;
  out_embed[idx] = nea / cs;
  if (idx == 0) out_loss[0] = scal[0] * (1.0f / ((float)NTOK * (float)DDIM));
}

extern "C" void kernel_launch(void* const* d_in, const int* in_sizes, int n_in,
                              void* d_out, int out_size, void* d_ws, size_t ws_size,
                              hipStream_t stream) {
  (void)in_sizes; (void)n_in; (void)out_size; (void)ws_size;
  const float* x            = (const float*)d_in[0];   // [NTOK, 512]
  const float* embed        = (const float*)d_in[1];   // [D, K]
  const float* cluster_size = (const float*)d_in[2];   // [K]
  const float* embed_avg    = (const float*)d_in[3];   // [D, K]

  float* out = (float*)d_out;
  float* out_quant = out;                               // 16777216
  float* out_indf  = out + 16777216;                    // 32768
  float* out_loss  = out + 16777216 + 32768;            // 1
  float* out_embed = out + 16777216 + 32768 + 1;        // 4194304 (odd offset)
  float* out_ncs   = out_embed + DK;                    // 8192
  float* out_avg   = out_ncs + KCODES;                  // 4194304

  float* ws = (float*)d_ws;
  float* esumT  = ws + WS_ESUMT;
  float* onehot = ws + WS_ONEHOT;
  float* e_norm = ws + WS_ENORM;
  float* scal   = ws + WS_SCAL;
  unsigned long long* partials = (unsigned long long*)(ws + WS_PART);
  float* embedT = ws + WS_EMBEDT;
  unsigned short* ehi = (unsigned short*)(ws + WS_EHI);
  unsigned short* elo = (unsigned short*)(ws + WS_ELO);

  // x hi/lo scratch lives in the out_quant region (exactly 2*NTOK*DDIM ushorts);
  // gather_stats_kernel overwrites it afterwards with the real quantize output.
  unsigned short* xhi = (unsigned short*)d_out;
  unsigned short* xlo = xhi + (size_t)NTOK * DDIM;

  hipMemsetAsync(d_ws, 0, WS_ZERO_BYTES, stream);

  split_x_kernel<<<NTOK * DDIM / 8 / 256, 256, 0, stream>>>(x, xhi, xlo);
  transpose_split_kernel<<<dim3(KCODES / 32, DDIM / 32), dim3(32, 8), 0, stream>>>(
      embed, embedT, ehi, elo, e_norm);

  argmin_mfma_kernel<<<dim3(64, 256), 256, 0, stream>>>(
      xhi, xlo, ehi, elo, e_norm, partials);

  gather_stats_kernel<<<NTOK, 128, 0, stream>>>(
      x, embedT, partials, out_quant, out_indf, esumT, onehot, scal);

  cluster_kernel<<<KCODES / 256, 256, 0, stream>>>(cluster_size, onehot, out_ncs, scal);

  finalize_kernel<<<DK / 256, 256, 0, stream>>>(
      embed_avg, esumT, out_ncs, scal, out_embed, out_avg, out_loss);
}

// Round 3
// 1576.236 us; speedup vs baseline: 2.6706x; 1.2667x over previous
//
#include <hip/hip_runtime.h>

#define NTOK   32768
#define DDIM   512
#define KCODES 8192
#define DK     (DDIM * KCODES)      // 4194304
#define DECAYF 0.8f
#define EPSF   1e-5f

using short8 = __attribute__((ext_vector_type(8))) short;
using f32x4  = __attribute__((ext_vector_type(4))) float;

// ---------------- ws layout (float offsets) ----------------
#define WS_ESUMT   0                          // [K][D] fp32 accum (zeroed)
#define WS_ONEHOT  DK                         // [K] (zeroed)
#define WS_ENORM   (DK + 8192)                // [K] (zeroed, atomic accum)
#define WS_SCAL    (DK + 16384)               // [16]: 0=loss, 1=nsum (zeroed)
#define WS_PART    (DK + 16400)               // NTOK u64, memset 0xFF (= u64 max)
#define WS_EMBEDT  (WS_PART + 2 * NTOK)       // [K][D] fp32 transposed codebook
#define WS_EHI     (WS_EMBEDT + DK)           // [K][D] bf16 hi (DK ushorts)
#define WS_ELO     (WS_EHI + DK / 2)          // [K][D] bf16 lo
#define WS_ZERO_BYTES ((size_t)(DK + 16400) * 4)

__device__ __forceinline__ unsigned short bf16rne(float f) {
  unsigned u = __float_as_uint(f);
  unsigned r = u + 0x7FFFu + ((u >> 16) & 1u);
  return (unsigned short)(r >> 16);
}

__device__ __forceinline__ void gload_lds16(const unsigned short* g, unsigned short* l) {
  __builtin_amdgcn_global_load_lds(
      (const __attribute__((address_space(1))) unsigned int*)g,
      (__attribute__((address_space(3))) unsigned int*)l, 16, 0, 0);
}

// ============ K1: split x into bf16 hi/lo ============
__global__ __launch_bounds__(256) void split_x_kernel(
    const float* __restrict__ x, unsigned short* __restrict__ hi,
    unsigned short* __restrict__ lo) {
  const size_t i = ((size_t)blockIdx.x * 256 + threadIdx.x) * 8;
  const float4 v0 = *(const float4*)&x[i];
  const float4 v1 = *(const float4*)&x[i + 4];
  const float v[8] = {v0.x, v0.y, v0.z, v0.w, v1.x, v1.y, v1.z, v1.w};
  unsigned short h[8], l[8];
#pragma unroll
  for (int j = 0; j < 8; ++j) {
    h[j] = bf16rne(v[j]);
    l[j] = bf16rne(v[j] - __uint_as_float((unsigned)h[j] << 16));
  }
  uint4 H, L;
  H.x = h[0] | ((unsigned)h[1] << 16); H.y = h[2] | ((unsigned)h[3] << 16);
  H.z = h[4] | ((unsigned)h[5] << 16); H.w = h[6] | ((unsigned)h[7] << 16);
  L.x = l[0] | ((unsigned)l[1] << 16); L.y = l[2] | ((unsigned)l[3] << 16);
  L.z = l[4] | ((unsigned)l[5] << 16); L.w = l[6] | ((unsigned)l[7] << 16);
  *(uint4*)&hi[i] = H;
  *(uint4*)&lo[i] = L;
}

// ============ K2: transpose embed [D][K]->[K][D] fp32 + bf16 hi/lo + e_norm ============
__global__ __launch_bounds__(256) void transpose_split_kernel(
    const float* __restrict__ embed, float* __restrict__ embedT,
    unsigned short* __restrict__ ehi, unsigned short* __restrict__ elo,
    float* __restrict__ e_norm) {
  __shared__ float tile[32][33];
  __shared__ float part[8][32];
  const int k0 = blockIdx.x * 32;
  const int d0 = blockIdx.y * 32;
  const int tx = threadIdx.x;   // 0..31
  const int ty = threadIdx.y;   // 0..7
  float sq = 0.f;
#pragma unroll
  for (int j = 0; j < 4; ++j) {
    const int dl = ty + j * 8;
    const float v = embed[(size_t)(d0 + dl) * KCODES + k0 + tx];
    tile[dl][tx] = v;
    sq += v * v;
  }
  part[ty][tx] = sq;
  __syncthreads();
  if (ty == 0) {
    float s = 0.f;
#pragma unroll
    for (int j = 0; j < 8; ++j) s += part[j][tx];
    atomicAdd(&e_norm[k0 + tx], s);
  }
#pragma unroll
  for (int j = 0; j < 4; ++j) {
    const int kl = ty + j * 8;
    const size_t idx = (size_t)(k0 + kl) * DDIM + d0 + tx;
    const float v = tile[tx][kl];
    embedT[idx] = v;
    const unsigned short h = bf16rne(v);
    ehi[idx] = h;
    elo[idx] = bf16rne(v - __uint_as_float((unsigned)h << 16));
  }
}

// ============ K3: fused 3-product bf16-split MFMA dist GEMM + argmin ============
// C-tile 128x128, BK=32, single D-loop staging Ahi/Alo/Bhi/Blo, 48 MFMA/iter.
// LDS XOR swizzle: colgroup c stored at c, holding global group c ^ ((row&15)>>1 & 3).
__global__ __launch_bounds__(256) void argmin_mfma_kernel(
    const unsigned short* __restrict__ xhi, const unsigned short* __restrict__ xlo,
    const unsigned short* __restrict__ ehi, const unsigned short* __restrict__ elo,
    const float* __restrict__ e_norm, unsigned long long* __restrict__ partials) {
  __shared__ unsigned short Ahs[128 * 32];   // 8 KB each
  __shared__ unsigned short Als[128 * 32];
  __shared__ unsigned short Bhs[128 * 32];
  __shared__ unsigned short Bls[128 * 32];

  const int t    = threadIdx.x;
  const int wid  = t >> 6;
  const int lid  = t & 63;
  const int kblk = blockIdx.x;              // 0..63
  const int tokbase = blockIdx.y * 128;
  const int kbase   = kblk * 128;

  const int wrow = wid >> 1, wcol = wid & 1;    // 2x2 wave grid, 64x64 each
  const int m16  = lid & 15, kq = lid >> 4;

  // staging lane mapping: row-within-chunk + swizzled global colgroup
  const int srow = lid >> 2;                                  // 0..15
  const int gcol = ((lid & 3) ^ ((srow >> 1) & 3)) * 8;       // swizzled source

  // ds_read swizzle for fragment loads
  const int fsw = (kq ^ ((m16 >> 1) & 3)) * 8;

  f32x4 acc[4][4];
#pragma unroll
  for (int i = 0; i < 4; ++i)
#pragma unroll
    for (int j = 0; j < 4; ++j) acc[i][j] = (f32x4)0.f;

  const unsigned short* Ahg = xhi + (size_t)tokbase * DDIM;
  const unsigned short* Alg = xlo + (size_t)tokbase * DDIM;
  const unsigned short* Bhg = ehi + (size_t)kbase * DDIM;
  const unsigned short* Blg = elo + (size_t)kbase * DDIM;

#pragma unroll 1
  for (int d0 = 0; d0 < DDIM; d0 += 32) {
    __syncthreads();
#pragma unroll
    for (int p = 0; p < 2; ++p) {
      const int chunk = wid + p * 4;                       // wave-uniform
      const size_t go = (size_t)(chunk * 16 + srow) * DDIM + d0 + gcol;
      gload_lds16(Ahg + go, &Ahs[chunk * 512]);
      gload_lds16(Alg + go, &Als[chunk * 512]);
      gload_lds16(Bhg + go, &Bhs[chunk * 512]);
      gload_lds16(Blg + go, &Bls[chunk * 512]);
    }
    __syncthreads();
    short8 bh[4], bl[4];
#pragma unroll
    for (int j = 0; j < 4; ++j) {
      const int r = (wcol * 64 + j * 16 + m16) * 32 + fsw;
      bh[j] = *(const short8*)&Bhs[r];
      bl[j] = *(const short8*)&Bls[r];
    }
#pragma unroll
    for (int i = 0; i < 4; ++i) {
      const int r = (wrow * 64 + i * 16 + m16) * 32 + fsw;
      const short8 ah = *(const short8*)&Ahs[r];
      const short8 al = *(const short8*)&Als[r];
#pragma unroll
      for (int j = 0; j < 4; ++j) {
        acc[i][j] = __builtin_amdgcn_mfma_f32_16x16x32_bf16(ah, bh[j], acc[i][j], 0, 0, 0);
        acc[i][j] = __builtin_amdgcn_mfma_f32_16x16x32_bf16(ah, bl[j], acc[i][j], 0, 0, 0);
        acc[i][j] = __builtin_amdgcn_mfma_f32_16x16x32_bf16(al, bh[j], acc[i][j], 0, 0, 0);
      }
    }
  }

  // ---- fused argmin epilogue: score = e_norm[k] - 2*dot ----
  float en[4];
#pragma unroll
  for (int j = 0; j < 4; ++j)
    en[j] = e_norm[kbase + wcol * 64 + j * 16 + m16];

  __syncthreads();
  unsigned long long* red = (unsigned long long*)Ahs;   // [128][2], 2 KB
#pragma unroll
  for (int i = 0; i < 4; ++i) {
#pragma unroll
    for (int r = 0; r < 4; ++r) {
      unsigned long long best = 0xFFFFFFFFFFFFFFFFull;
#pragma unroll
      for (int j = 0; j < 4; ++j) {
        const float s = en[j] - 2.0f * acc[i][j][r];
        unsigned u = __float_as_uint(s);
        u = (u & 0x80000000u) ? ~u : (u | 0x80000000u);  // orderable bits
        const unsigned k = (unsigned)(kbase + wcol * 64 + j * 16 + m16);
        const unsigned long long c = ((unsigned long long)u << 32) | k;
        best = (c < best) ? c : best;
      }
#pragma unroll
      for (int s = 1; s < 16; s <<= 1) {
        const unsigned long long c = __shfl_xor(best, s);
        best = (c < best) ? c : best;
      }
      if (m16 == 0)
        red[(wrow * 64 + i * 16 + kq * 4 + r) * 2 + wcol] = best;
    }
  }
  __syncthreads();
  if (t < 128) {
    const unsigned long long a0 = red[t * 2], a1 = red[t * 2 + 1];
    const unsigned long long m = (a0 < a1) ? a0 : a1;
    atomicMin(&partials[tokbase + t], m);
  }
}

// ============ K4: gather quantize + EMA scatter stats + loss ============
__global__ __launch_bounds__(128) void gather_stats_kernel(
    const float* __restrict__ x, const float* __restrict__ embedT,
    const unsigned long long* __restrict__ partials,
    float* __restrict__ quant_out, float* __restrict__ indf_out,
    float* __restrict__ embed_sumT, float* __restrict__ onehot,
    float* __restrict__ scal) {
  const int n = blockIdx.x;
  __shared__ int s_ind;
  __shared__ float wsum[2];
  if (threadIdx.x == 0) {
    const int k = (int)(partials[n] & 0xFFFFFFFFull);
    s_ind = k;
    indf_out[n] = (float)k;
    atomicAdd(&onehot[k], 1.0f);
  }
  __syncthreads();
  const int k = s_ind;
  const int d4 = threadIdx.x * 4;    // 128 threads * 4 = 512 = DDIM
  const float4 e  = *(const float4*)&embedT[(size_t)k * DDIM + d4];
  const float4 xv = *(const float4*)&x[(size_t)n * DDIM + d4];
  *(float4*)&quant_out[(size_t)n * DDIM + d4] = e;
  atomicAdd(&embed_sumT[(size_t)k * DDIM + d4 + 0], xv.x);
  atomicAdd(&embed_sumT[(size_t)k * DDIM + d4 + 1], xv.y);
  atomicAdd(&embed_sumT[(size_t)k * DDIM + d4 + 2], xv.z);
  atomicAdd(&embed_sumT[(size_t)k * DDIM + d4 + 3], xv.w);
  const float dx0 = e.x - xv.x, dx1 = e.y - xv.y, dx2 = e.z - xv.z, dx3 = e.w - xv.w;
  float ls = dx0 * dx0 + dx1 * dx1 + dx2 * dx2 + dx3 * dx3;
#pragma unroll
  for (int off = 32; off > 0; off >>= 1) ls += __shfl_down(ls, off);
  if ((threadIdx.x & 63) == 0) wsum[threadIdx.x >> 6] = ls;
  __syncthreads();
  if (threadIdx.x == 0) atomicAdd(&scal[0], wsum[0] + wsum[1]);
}

// ============ K5: cluster-size EMA + total-count reduction ============
__global__ __launch_bounds__(256) void cluster_kernel(
    const float* __restrict__ cluster_size, const float* __restrict__ onehot,
    float* __restrict__ ncs_out, float* __restrict__ scal) {
  const int k = blockIdx.x * 256 + threadIdx.x;
  const float v = cluster_size[k] * DECAYF + (1.0f - DECAYF) * onehot[k];
  ncs_out[k] = v;
  float s = v;
#pragma unroll
  for (int off = 32; off > 0; off >>= 1) s += __shfl_down(s, off);
  __shared__ float w[4];
  if ((threadIdx.x & 63) == 0) w[threadIdx.x >> 6] = s;
  __syncthreads();
  if (threadIdx.x == 0) atomicAdd(&scal[1], w[0] + w[1] + w[2] + w[3]);
}

// ============ K6: new_embed_avg + new_embed + loss (odd offset -> scalar) ============
__global__ __launch_bounds__(256) void finalize_kernel(
    const float* __restrict__ embed_avg, const float* __restrict__ embed_sumT,
    const float* __restrict__ ncs, const float* __restrict__ scal,
    float* __restrict__ out_embed, float* __restrict__ out_avg,
    float* __restrict__ out_loss) {
  const int idx = blockIdx.x * 256 + threadIdx.x;   // [D][K] layout
  const int d = idx >> 13;
  const int k = idx & (KCODES - 1);
  const float ea = embed_avg[idx];
  const float es = embed_sumT[(size_t)k * DDIM + d];
  const float nea = DECAYF * ea + (1.0f - DECAYF) * es;
  out_avg[idx] = nea;
  const float nsum = scal[1];
  const float cs = (ncs[k] + EPSF) / (nsum + (float)KCODES * EPSF) * nsum;
  out_embed[idx] = nea / cs;
  if (idx == 0) out_loss[0] = scal[0] * (1.0f / ((float)NTOK * (float)DDIM));
}

extern "C" void kernel_launch(void* const* d_in, const int* in_sizes, int n_in,
                              void* d_out, int out_size, void* d_ws, size_t ws_size,
                              hipStream_t stream) {
  (void)in_sizes; (void)n_in; (void)out_size; (void)ws_size;
  const float* x            = (const float*)d_in[0];   // [NTOK, 512]
  const float* embed        = (const float*)d_in[1];   // [D, K]
  const float* cluster_size = (const float*)d_in[2];   // [K]
  const float* embed_avg    = (const float*)d_in[3];   // [D, K]

  float* out = (float*)d_out;
  float* out_quant = out;                               // 16777216
  float* out_indf  = out + 16777216;                    // 32768
  float* out_loss  = out + 16777216 + 32768;            // 1
  float* out_embed = out + 16777216 + 32768 + 1;        // 4194304 (odd offset)
  float* out_ncs   = out_embed + DK;                    // 8192
  float* out_avg   = out_ncs + KCODES;                  // 4194304

  float* ws = (float*)d_ws;
  float* esumT  = ws + WS_ESUMT;
  float* onehot = ws + WS_ONEHOT;
  float* e_norm = ws + WS_ENORM;
  float* scal   = ws + WS_SCAL;
  unsigned long long* partials = (unsigned long long*)(ws + WS_PART);
  float* embedT = ws + WS_EMBEDT;
  unsigned short* ehi = (unsigned short*)(ws + WS_EHI);
  unsigned short* elo = (unsigned short*)(ws + WS_ELO);

  // x hi/lo scratch lives in the out_quant region; overwritten by gather later.
  unsigned short* xhi = (unsigned short*)d_out;
  unsigned short* xlo = xhi + (size_t)NTOK * DDIM;

  hipMemsetAsync(d_ws, 0, WS_ZERO_BYTES, stream);
  hipMemsetAsync((char*)d_ws + (size_t)WS_PART * 4, 0xFF, (size_t)NTOK * 8, stream);

  split_x_kernel<<<NTOK * DDIM / 8 / 256, 256, 0, stream>>>(x, xhi, xlo);
  transpose_split_kernel<<<dim3(KCODES / 32, DDIM / 32), dim3(32, 8), 0, stream>>>(
      embed, embedT, ehi, elo, e_norm);

  argmin_mfma_kernel<<<dim3(64, 256), 256, 0, stream>>>(
      xhi, xlo, ehi, elo, e_norm, partials);

  gather_stats_kernel<<<NTOK, 128, 0, stream>>>(
      x, embedT, partials, out_quant, out_indf, esumT, onehot, scal);

  cluster_kernel<<<KCODES / 256, 256, 0, stream>>>(cluster_size, onehot, out_ncs, scal);

  finalize_kernel<<<DK / 256, 256, 0, stream>>>(
      embed_avg, esumT, out_ncs, scal, out_embed, out_avg, out_loss);
}